// Round 12
// baseline (75.070 us; speedup 1.0000x reference)
//
#include <hip/hip_runtime.h>

#define NHEADS 4
#define HDIM   64
#define BATCH  8
#define SEQ    1024
#define CH     256   // H*hd = in_dim = out_dim
#define LOG2E  1.4426950408889634f
#define LDP    132           // LDS row stride in floats

typedef float  f32x4  __attribute__((ext_vector_type(4)));
typedef __bf16 bf16x8 __attribute__((ext_vector_type(8)));
typedef short  s16x8  __attribute__((ext_vector_type(8)));
union FU { s16x8 s; bf16x8 b; };

__device__ inline unsigned short f2bf(float f) {
    unsigned u = __float_as_uint(f);
    return (unsigned short)((u + 0x7fffu + ((u >> 16) & 1u)) >> 16);
}

// ---------------------------------------------------------------------------
// K0: WpT[ch][k] = bf16(Wp[k][ch])
// ---------------------------------------------------------------------------
__global__ __launch_bounds__(256) void wpt_cast(const float* __restrict__ Wp,
                                                unsigned short* __restrict__ WpT) {
    __shared__ float T[32][33];
    const int t = threadIdx.x;
    const int kt = blockIdx.x * 32, ct = blockIdx.y * 32;
    const int r = t >> 3, c4 = (t & 7) * 4;
    float4 v = *reinterpret_cast<const float4*>(&Wp[(size_t)(kt + r) * CH + ct + c4]);
    T[r][c4 + 0] = v.x; T[r][c4 + 1] = v.y; T[r][c4 + 2] = v.z; T[r][c4 + 3] = v.w;
    __syncthreads();
    unsigned p0 = (unsigned)f2bf(T[c4 + 0][r]) | ((unsigned)f2bf(T[c4 + 1][r]) << 16);
    unsigned p1 = (unsigned)f2bf(T[c4 + 2][r]) | ((unsigned)f2bf(T[c4 + 3][r]) << 16);
    uint2 o = make_uint2(p0, p1);
    *reinterpret_cast<uint2*>(&WpT[(size_t)(ct + r) * CH + kt + c4]) = o;
}

// ---------------------------------------------------------------------------
// K1: projT = (x @ Wp)^T via MFMA. Block = 16 x-rows, wave w = head w.
// ---------------------------------------------------------------------------
__global__ __launch_bounds__(256) void proj_fused(const float* __restrict__ x,
                                                  const unsigned short* __restrict__ WpT,
                                                  const float* __restrict__ Ws,
                                                  unsigned short* __restrict__ projT,
                                                  float* __restrict__ sl,
                                                  float* __restrict__ sr) {
    const int t = threadIdx.x, w = t >> 6, l = t & 63, il = l & 15, g = l >> 4;
    const int row0 = blockIdx.x * 16;
    const int b = row0 >> 10, n0 = row0 & 1023;

    const unsigned short* Ap = WpT + (size_t)(w * 64 + il) * CH + g * 8;
    const float*          Bp = x + (size_t)(row0 + il) * CH + g * 8;

    f32x4 acc[4] = {};
#pragma unroll
    for (int kt = 0; kt < 8; ++kt) {
        FU a[4], bb;
#pragma unroll
        for (int ai = 0; ai < 4; ++ai)
            a[ai].s = *reinterpret_cast<const s16x8*>(Ap + (size_t)ai * 16 * CH + kt * 32);
        float4 v0 = *reinterpret_cast<const float4*>(Bp + kt * 32);
        float4 v1 = *reinterpret_cast<const float4*>(Bp + kt * 32 + 4);
        bb.b[0] = (__bf16)v0.x; bb.b[1] = (__bf16)v0.y;
        bb.b[2] = (__bf16)v0.z; bb.b[3] = (__bf16)v0.w;
        bb.b[4] = (__bf16)v1.x; bb.b[5] = (__bf16)v1.y;
        bb.b[6] = (__bf16)v1.z; bb.b[7] = (__bf16)v1.w;
#pragma unroll
        for (int ai = 0; ai < 4; ++ai)
            acc[ai] = __builtin_amdgcn_mfma_f32_16x16x32_bf16(a[ai].b, bb.b, acc[ai], 0, 0, 0);
    }

    unsigned short* pTb = projT + ((size_t)(b * NHEADS + w) * HDIM) * SEQ + n0 + il;
#pragma unroll
    for (int ai = 0; ai < 4; ++ai)
#pragma unroll
        for (int q = 0; q < 4; ++q)
            pTb[(size_t)(ai * 16 + g * 4 + q) * SEQ] = f2bf(acc[ai][q]);

    float pl = 0.f, pr = 0.f;
#pragma unroll
    for (int ai = 0; ai < 4; ++ai) {
        float4 wlv = *reinterpret_cast<const float4*>(&Ws[ai * 16 + g * 4]);
        float4 wrv = *reinterpret_cast<const float4*>(&Ws[HDIM + ai * 16 + g * 4]);
        pl += acc[ai][0] * wlv.x + acc[ai][1] * wlv.y + acc[ai][2] * wlv.z + acc[ai][3] * wlv.w;
        pr += acc[ai][0] * wrv.x + acc[ai][1] * wrv.y + acc[ai][2] * wrv.z + acc[ai][3] * wrv.w;
    }
    pl += __shfl_xor(pl, 16); pl += __shfl_xor(pl, 32);
    pr += __shfl_xor(pr, 16); pr += __shfl_xor(pr, 32);
    if (l < 16) {
        sl[(size_t)(b * NHEADS + w) * SEQ + n0 + il] = pl * LOG2E;
        sr[(size_t)(b * NHEADS + w) * SEQ + n0 + il] = pr * LOG2E;
    }
}

// ---------------------------------------------------------------------------
// K3: attention v8. Block = 1024 threads = 16 waves (head h = w&3, m-quarter
//     mq = w>>2), i-tile 16, XCD-batch mapping (b = blockIdx.x & 7).
//     Grid 512 -> 2 blocks/CU -> 32 waves/CU target (launch_bounds(1024,8)
//     caps VGPR at 64; den on VALU+shfl to stay under).
//     2 staging fills of [4 quarters][16 rows][128 m] fp32 (coalesced, fused
//     out_adj copy). Cross-quarter combine in LDS overlaying the stage buffer.
// ---------------------------------------------------------------------------
template <bool FUSE_ADJ>
__global__ __launch_bounds__(1024, 8) void attn8(const float* __restrict__ x,
                                                 const float* __restrict__ adj,
                                                 const unsigned short* __restrict__ projT,
                                                 const float* __restrict__ sl,
                                                 const float* __restrict__ sr,
                                                 const float* __restrict__ Ws,
                                                 const float* __restrict__ bias,
                                                 float* __restrict__ out,
                                                 float* __restrict__ out_adj) {
    __shared__ __align__(16) float smem[2 * 4 * 16 * LDP];   // 67.6 KB

    const int t = threadIdx.x;
    const int w = t >> 6, l = t & 63, il = l & 15, g = l >> 4;
    const int h = w & 3, mq = w >> 2;
    const int b  = blockIdx.x & 7;          // XCD-aligned batch
    const int i0 = (blockIdx.x >> 3) * 16;
    const float wa2 = Ws[2 * HDIM] * LOG2E;

    // staging map: thread t -> quarter sq, row srow, col scol (float4 x2)
    const int sq = t >> 8, srow = (t >> 4) & 15, scol = (t & 15) * 4;
    const size_t abase = ((size_t)(b * SEQ + i0 + srow)) * SEQ + sq * 256 + scol;

    const int bh = b * NHEADS + h;
    const float sl_i = sl[(size_t)bh * SEQ + i0 + il];
    const float* srp = sr + (size_t)bh * SEQ + mq * 256;
    const unsigned short* pT = projT + ((size_t)bh * HDIM + il) * SEQ + mq * 256 + g * 8;

    f32x4 acc[4] = {};
    float den = 0.f;

    // ---- stage fill 0 (m-cols [sq*256, +128)) ----
    {
        float4 c0 = *reinterpret_cast<const float4*>(adj + abase);
        float4 c1 = *reinterpret_cast<const float4*>(adj + abase + 64);
        if (FUSE_ADJ) {
            *reinterpret_cast<float4*>(out_adj + abase)      = c0;
            *reinterpret_cast<float4*>(out_adj + abase + 64) = c1;
        }
        float* dst = &smem[((0 * 4 + sq) * 16 + srow) * LDP + scol];
        *reinterpret_cast<float4*>(dst)      = c0;
        *reinterpret_cast<float4*>(dst + 64) = c1;
    }
    __syncthreads();

#pragma unroll
    for (int c = 0; c < 2; ++c) {
        // compute chunk c: global m = mq*256 + c*128 + mk
        const float* aT = &smem[((c * 4 + mq) * 16 + il) * LDP];
        const int mo = c * 128;
#pragma unroll
        for (int kq = 0; kq < 4; ++kq) {
            const int mk = kq * 32 + g * 8;
            float4 a0 = *reinterpret_cast<const float4*>(aT + mk);
            float4 a1 = *reinterpret_cast<const float4*>(aT + mk + 4);
            float4 s0 = *reinterpret_cast<const float4*>(srp + mo + mk);
            float4 s1 = *reinterpret_cast<const float4*>(srp + mo + mk + 4);
            float aj[8] = {a0.x, a0.y, a0.z, a0.w, a1.x, a1.y, a1.z, a1.w};
            float sv[8] = {s0.x, s0.y, s0.z, s0.w, s1.x, s1.y, s1.z, s1.w};
            FU af;
#pragma unroll
            for (int j = 0; j < 8; ++j) {
                float s = fmaf(aj[j], wa2, sl_i + sv[j]);
                s = __builtin_amdgcn_fmed3f(s, 0.2f * s, 86.5617f);
                float e = (aj[j] <= 1e-5f) ? 0.f : __builtin_amdgcn_exp2f(s);
                den += e;
                af.b[j] = (__bf16)e;
            }
            FU b0, b1, b2, b3;
            b0.s = *reinterpret_cast<const s16x8*>(pT + mo + kq * 32);
            b1.s = *reinterpret_cast<const s16x8*>(pT + mo + kq * 32 + (size_t)16 * SEQ);
            b2.s = *reinterpret_cast<const s16x8*>(pT + mo + kq * 32 + (size_t)32 * SEQ);
            b3.s = *reinterpret_cast<const s16x8*>(pT + mo + kq * 32 + (size_t)48 * SEQ);
            acc[0] = __builtin_amdgcn_mfma_f32_16x16x32_bf16(af.b, b0.b, acc[0], 0, 0, 0);
            acc[1] = __builtin_amdgcn_mfma_f32_16x16x32_bf16(af.b, b1.b, acc[1], 0, 0, 0);
            acc[2] = __builtin_amdgcn_mfma_f32_16x16x32_bf16(af.b, b2.b, acc[2], 0, 0, 0);
            acc[3] = __builtin_amdgcn_mfma_f32_16x16x32_bf16(af.b, b3.b, acc[3], 0, 0, 0);
        }
        // stage fill 1 after computing fill 0 (separate LDS region, no hazard)
        if (c == 0) {
            float4 c0 = *reinterpret_cast<const float4*>(adj + abase + 128);
            float4 c1 = *reinterpret_cast<const float4*>(adj + abase + 128 + 64);
            if (FUSE_ADJ) {
                *reinterpret_cast<float4*>(out_adj + abase + 128)      = c0;
                *reinterpret_cast<float4*>(out_adj + abase + 128 + 64) = c1;
            }
            float* dst = &smem[((1 * 4 + sq) * 16 + srow) * LDP + scol];
            *reinterpret_cast<float4*>(dst)      = c0;
            *reinterpret_cast<float4*>(dst + 64) = c1;
        }
        __syncthreads();
    }

    // den: reduce across g-slices -> lane (il,*) holds quarter-den for row il
    den += __shfl_xor(den, 16);
    den += __shfl_xor(den, 32);

    // ---- cross-quarter combine (part overlays smem; all reads done) ----
    float (*part)[NHEADS][16][68] = reinterpret_cast<float (*)[NHEADS][16][68]>(smem);
    if (mq > 0) {
#pragma unroll
        for (int bj = 0; bj < 4; ++bj)
#pragma unroll
            for (int q = 0; q < 4; ++q)
                part[mq - 1][h][g * 4 + q][bj * 16 + il] = acc[bj][q];
        if (l < 16) part[mq - 1][h][l][64] = den;
    }
    __syncthreads();
    if (mq == 0) {
        const float* bb = bias + h * HDIM;
#pragma unroll
        for (int q = 0; q < 4; ++q) {
            const int row = g * 4 + q;
            float dsum = __shfl(den, row) + part[0][h][row][64]
                       + part[1][h][row][64] + part[2][h][row][64];
            const float inv = 1.f / dsum;
            const size_t ob = ((size_t)(b * SEQ + i0 + row)) * CH + h * HDIM + il;
#pragma unroll
            for (int bj = 0; bj < 4; ++bj) {
                float m = acc[bj][q] + part[0][h][row][bj * 16 + il]
                        + part[1][h][row][bj * 16 + il] + part[2][h][row][bj * 16 + il];
                float v = fmaf(m, inv, x[ob + bj * 16] + bb[bj * 16 + il]);
                out[ob + bj * 16] = fmaxf(v, 0.5f * v);
            }
        }
    }
}

// ---------------------------------------------------------------------------
// K4 (fallback): copy adj into output chunk 2
// ---------------------------------------------------------------------------
__global__ void adjcopy(const float* __restrict__ adj, float* __restrict__ dst, int n4) {
    int idx = blockIdx.x * blockDim.x + threadIdx.x;
    int stride = gridDim.x * blockDim.x;
    const float4* s = reinterpret_cast<const float4*>(adj);
    float4* d = reinterpret_cast<float4*>(dst);
    for (int i = idx; i < n4; i += stride) d[i] = s[i];
}

extern "C" void kernel_launch(void* const* d_in, const int* in_sizes, int n_in,
                              void* d_out, int out_size, void* d_ws, size_t ws_size,
                              hipStream_t stream) {
    const float* x    = (const float*)d_in[0];
    const float* adj  = (const float*)d_in[1];
    const float* Wp   = (const float*)d_in[2];
    const float* Ws   = (const float*)d_in[3];
    const float* bias = (const float*)d_in[4];
    float* out     = (float*)d_out;
    float* out_adj = out + (size_t)BATCH * SEQ * CH;

    const size_t nProj = (size_t)BATCH * SEQ * CH;
    const size_t nSc   = (size_t)BATCH * NHEADS * SEQ;
    const size_t need  = CH * CH * 2 + nProj * 2 + 2 * nSc * 4;
    const bool use_ws  = (ws_size >= need);
    char* scratch = use_ws ? (char*)d_ws : (char*)out_adj;
    unsigned short* WpT   = (unsigned short*)scratch;
    unsigned short* projT = (unsigned short*)(scratch + (size_t)CH * CH * 2);
    float*          sl    = (float*)(scratch + (size_t)CH * CH * 2 + nProj * 2);
    float*          sr    = sl + nSc;

    wpt_cast<<<dim3(8, 8), 256, 0, stream>>>(Wp, WpT);
    proj_fused<<<dim3(512), 256, 0, stream>>>(x, WpT, Ws, projT, sl, sr);
    if (use_ws) {
        attn8<true><<<dim3(512), 1024, 0, stream>>>(
            x, adj, projT, sl, sr, Ws, bias, out, out_adj);
    } else {
        attn8<false><<<dim3(512), 1024, 0, stream>>>(
            x, adj, projT, sl, sr, Ws, bias, out, out_adj);
        adjcopy<<<2048, 256, 0, stream>>>(adj, out_adj, (BATCH * SEQ * SEQ) / 4);
    }
}

// Round 13
// 63.878 us; speedup vs baseline: 1.1752x; 1.1752x over previous
//
#include <hip/hip_runtime.h>

#define NHEADS 4
#define HDIM   64
#define BATCH  8
#define SEQ    1024
#define CH     256   // H*hd = in_dim = out_dim
#define LOG2E  1.4426950408889634f
#define MC     128           // m-chunk per staging step
#define NC     (SEQ / MC)    // 8 chunks
#define LDP    132           // LDS row stride in floats

typedef float  f32x4  __attribute__((ext_vector_type(4)));
typedef __bf16 bf16x8 __attribute__((ext_vector_type(8)));
typedef short  s16x8  __attribute__((ext_vector_type(8)));
union FU { s16x8 s; bf16x8 b; };

__device__ inline unsigned short f2bf(float f) {
    unsigned u = __float_as_uint(f);
    return (unsigned short)((u + 0x7fffu + ((u >> 16) & 1u)) >> 16);
}

// ---------------------------------------------------------------------------
// K0: WpT[ch][k] = bf16(Wp[k][ch])
// ---------------------------------------------------------------------------
__global__ __launch_bounds__(256) void wpt_cast(const float* __restrict__ Wp,
                                                unsigned short* __restrict__ WpT) {
    __shared__ float T[32][33];
    const int t = threadIdx.x;
    const int kt = blockIdx.x * 32, ct = blockIdx.y * 32;
    const int r = t >> 3, c4 = (t & 7) * 4;
    float4 v = *reinterpret_cast<const float4*>(&Wp[(size_t)(kt + r) * CH + ct + c4]);
    T[r][c4 + 0] = v.x; T[r][c4 + 1] = v.y; T[r][c4 + 2] = v.z; T[r][c4 + 3] = v.w;
    __syncthreads();
    unsigned p0 = (unsigned)f2bf(T[c4 + 0][r]) | ((unsigned)f2bf(T[c4 + 1][r]) << 16);
    unsigned p1 = (unsigned)f2bf(T[c4 + 2][r]) | ((unsigned)f2bf(T[c4 + 3][r]) << 16);
    uint2 o = make_uint2(p0, p1);
    *reinterpret_cast<uint2*>(&WpT[(size_t)(ct + r) * CH + kt + c4]) = o;
}

// ---------------------------------------------------------------------------
// K1: projT = (x @ Wp)^T via MFMA, ALL x HBM loads hoisted to a register
//     batch up front (one HBM latency per block instead of 8).
// ---------------------------------------------------------------------------
__global__ __launch_bounds__(256, 2) void proj_fused(const float* __restrict__ x,
                                                     const unsigned short* __restrict__ WpT,
                                                     const float* __restrict__ Ws,
                                                     unsigned short* __restrict__ projT,
                                                     float* __restrict__ sl,
                                                     float* __restrict__ sr) {
    const int t = threadIdx.x, w = t >> 6, l = t & 63, il = l & 15, g = l >> 4;
    const int row0 = blockIdx.x * 16;
    const int b = row0 >> 10, n0 = row0 & 1023;

    const unsigned short* Ap = WpT + (size_t)(w * 64 + il) * CH + g * 8;
    const float*          Bp = x + (size_t)(row0 + il) * CH + g * 8;

    // hoist all x loads (the HBM stream): 16 float4
    float4 xv[8][2];
#pragma unroll
    for (int kt = 0; kt < 8; ++kt) {
        xv[kt][0] = *reinterpret_cast<const float4*>(Bp + kt * 32);
        xv[kt][1] = *reinterpret_cast<const float4*>(Bp + kt * 32 + 4);
    }

    f32x4 acc[4] = {};
#pragma unroll
    for (int kt = 0; kt < 8; ++kt) {
        FU a[4], bb;
#pragma unroll
        for (int ai = 0; ai < 4; ++ai)
            a[ai].s = *reinterpret_cast<const s16x8*>(Ap + (size_t)ai * 16 * CH + kt * 32);
        bb.b[0] = (__bf16)xv[kt][0].x; bb.b[1] = (__bf16)xv[kt][0].y;
        bb.b[2] = (__bf16)xv[kt][0].z; bb.b[3] = (__bf16)xv[kt][0].w;
        bb.b[4] = (__bf16)xv[kt][1].x; bb.b[5] = (__bf16)xv[kt][1].y;
        bb.b[6] = (__bf16)xv[kt][1].z; bb.b[7] = (__bf16)xv[kt][1].w;
#pragma unroll
        for (int ai = 0; ai < 4; ++ai)
            acc[ai] = __builtin_amdgcn_mfma_f32_16x16x32_bf16(a[ai].b, bb.b, acc[ai], 0, 0, 0);
    }

    unsigned short* pTb = projT + ((size_t)(b * NHEADS + w) * HDIM) * SEQ + n0 + il;
#pragma unroll
    for (int ai = 0; ai < 4; ++ai)
#pragma unroll
        for (int q = 0; q < 4; ++q)
            pTb[(size_t)(ai * 16 + g * 4 + q) * SEQ] = f2bf(acc[ai][q]);

    float pl = 0.f, pr = 0.f;
#pragma unroll
    for (int ai = 0; ai < 4; ++ai) {
        float4 wlv = *reinterpret_cast<const float4*>(&Ws[ai * 16 + g * 4]);
        float4 wrv = *reinterpret_cast<const float4*>(&Ws[HDIM + ai * 16 + g * 4]);
        pl += acc[ai][0] * wlv.x + acc[ai][1] * wlv.y + acc[ai][2] * wlv.z + acc[ai][3] * wlv.w;
        pr += acc[ai][0] * wrv.x + acc[ai][1] * wrv.y + acc[ai][2] * wrv.z + acc[ai][3] * wrv.w;
    }
    pl += __shfl_xor(pl, 16); pl += __shfl_xor(pl, 32);
    pr += __shfl_xor(pr, 16); pr += __shfl_xor(pr, 32);
    if (l < 16) {
        sl[(size_t)(b * NHEADS + w) * SEQ + n0 + il] = pl * LOG2E;
        sr[(size_t)(b * NHEADS + w) * SEQ + n0 + il] = pr * LOG2E;
    }
}

// ---------------------------------------------------------------------------
// K3: attention v10 = attn4x + FAT-STEP chunk body: batch ALL chunk operands
//     into registers first (8 LDS f4 + 8 sr f4 + 16 projT s16x8 ~ 128 VGPR),
//     then all e-chains, then all MFMAs -> one latency exposure per chunk.
//     XCD batch mapping, coalesced dbuf staging, fused out_adj copy kept.
// ---------------------------------------------------------------------------
template <bool FUSE_ADJ>
__global__ __launch_bounds__(256, 2) void attn10(const float* __restrict__ x,
                                                 const float* __restrict__ adj,
                                                 const unsigned short* __restrict__ projT,
                                                 const float* __restrict__ sl,
                                                 const float* __restrict__ sr,
                                                 const float* __restrict__ Ws,
                                                 const float* __restrict__ bias,
                                                 float* __restrict__ out,
                                                 float* __restrict__ out_adj) {
    __shared__ __align__(16) float abuf[2][16][LDP];

    const int t = threadIdx.x;
    const int h = t >> 6, l = t & 63, il = l & 15, g = l >> 4;
    const int b  = blockIdx.x & 7;        // XCD-aligned batch
    const int i0 = (blockIdx.x >> 3) * 16;
    const float wa2 = Ws[2 * HDIM] * LOG2E;

    const int str = t >> 4;
    const int stc = (t & 15) * 4;
    const size_t astg = ((size_t)(b * SEQ + i0 + str)) * SEQ + stc;

    const float sl_i = sl[(size_t)(b * NHEADS + h) * SEQ + i0 + il];
    const float* srp = sr + (size_t)(b * NHEADS + h) * SEQ;
    const unsigned short* pT = projT + ((size_t)(b * NHEADS + h) * HDIM + il) * SEQ + g * 8;

    FU ones;
#pragma unroll
    for (int j = 0; j < 8; ++j) ones.s[j] = (short)0x3F80;

    f32x4 acc[4] = {};
    f32x4 dacc = {};

    float4 c00 = *reinterpret_cast<const float4*>(adj + astg);
    float4 c01 = *reinterpret_cast<const float4*>(adj + astg + 64);
    float4 cur0 = *reinterpret_cast<const float4*>(adj + astg + MC);
    float4 cur1 = *reinterpret_cast<const float4*>(adj + astg + MC + 64);
    if (FUSE_ADJ) {
        *reinterpret_cast<float4*>(out_adj + astg)      = c00;
        *reinterpret_cast<float4*>(out_adj + astg + 64) = c01;
    }
    *reinterpret_cast<float4*>(&abuf[0][str][stc])      = c00;
    *reinterpret_cast<float4*>(&abuf[0][str][stc + 64]) = c01;
    __syncthreads();

    for (int c = 0; c < NC; ++c) {
        // (1) issue next-next staging loads
        float4 nx0 = {}, nx1 = {};
        if (c + 2 < NC) {
            nx0 = *reinterpret_cast<const float4*>(adj + astg + (size_t)(c + 2) * MC);
            nx1 = *reinterpret_cast<const float4*>(adj + astg + (size_t)(c + 2) * MC + 64);
        }
        const float* aT = &abuf[c & 1][il][0];
        const int mt = c * MC;

        // (2) batch-load ALL chunk operands into registers
        float4 av[4][2], sv4[4][2];
        FU B[4][4];
#pragma unroll
        for (int kq = 0; kq < 4; ++kq) {
            const int mk = kq * 32 + g * 8;
            av[kq][0]  = *reinterpret_cast<const float4*>(aT + mk);
            av[kq][1]  = *reinterpret_cast<const float4*>(aT + mk + 4);
            sv4[kq][0] = *reinterpret_cast<const float4*>(srp + mt + mk);
            sv4[kq][1] = *reinterpret_cast<const float4*>(srp + mt + mk + 4);
        }
#pragma unroll
        for (int kq = 0; kq < 4; ++kq) {
#pragma unroll
            for (int bj = 0; bj < 4; ++bj)
                B[kq][bj].s = *reinterpret_cast<const s16x8*>(pT + mt + kq * 32 + (size_t)(bj * 16) * SEQ);
        }

        // (3) all e-chains
        FU af[4];
#pragma unroll
        for (int kq = 0; kq < 4; ++kq) {
            float aj[8] = {av[kq][0].x, av[kq][0].y, av[kq][0].z, av[kq][0].w,
                           av[kq][1].x, av[kq][1].y, av[kq][1].z, av[kq][1].w};
            float sv[8] = {sv4[kq][0].x, sv4[kq][0].y, sv4[kq][0].z, sv4[kq][0].w,
                           sv4[kq][1].x, sv4[kq][1].y, sv4[kq][1].z, sv4[kq][1].w};
#pragma unroll
            for (int j = 0; j < 8; ++j) {
                float s = fmaf(aj[j], wa2, sl_i + sv[j]);
                s = __builtin_amdgcn_fmed3f(s, 0.2f * s, 86.5617f);
                float e = (aj[j] <= 1e-5f) ? 0.f : __builtin_amdgcn_exp2f(s);
                af[kq].b[j] = (__bf16)e;
            }
        }

        // (4) all MFMAs
#pragma unroll
        for (int kq = 0; kq < 4; ++kq) {
            acc[0] = __builtin_amdgcn_mfma_f32_16x16x32_bf16(af[kq].b, B[kq][0].b, acc[0], 0, 0, 0);
            acc[1] = __builtin_amdgcn_mfma_f32_16x16x32_bf16(af[kq].b, B[kq][1].b, acc[1], 0, 0, 0);
            acc[2] = __builtin_amdgcn_mfma_f32_16x16x32_bf16(af[kq].b, B[kq][2].b, acc[2], 0, 0, 0);
            acc[3] = __builtin_amdgcn_mfma_f32_16x16x32_bf16(af[kq].b, B[kq][3].b, acc[3], 0, 0, 0);
            dacc   = __builtin_amdgcn_mfma_f32_16x16x32_bf16(af[kq].b, ones.b,   dacc,   0, 0, 0);
        }

        // (5) stage chunk c+1 + fused out_adj write
        if (c + 1 < NC) {
            if (FUSE_ADJ) {
                *reinterpret_cast<float4*>(out_adj + astg + (size_t)(c + 1) * MC)      = cur0;
                *reinterpret_cast<float4*>(out_adj + astg + (size_t)(c + 1) * MC + 64) = cur1;
            }
            *reinterpret_cast<float4*>(&abuf[(c + 1) & 1][str][stc])      = cur0;
            *reinterpret_cast<float4*>(&abuf[(c + 1) & 1][str][stc + 64]) = cur1;
        }
        __syncthreads();
        cur0 = nx0; cur1 = nx1;
    }

    const float* bb = bias + h * HDIM;
#pragma unroll
    for (int q = 0; q < 4; ++q) {
        const float inv = 1.f / dacc[q];
        const size_t ob = ((size_t)(b * SEQ + i0 + g * 4 + q)) * CH + h * HDIM + il;
#pragma unroll
        for (int bj = 0; bj < 4; ++bj) {
            float v = fmaf(acc[bj][q], inv, x[ob + bj * 16] + bb[bj * 16 + il]);
            out[ob + bj * 16] = fmaxf(v, 0.5f * v);
        }
    }
}

// ---------------------------------------------------------------------------
// K4 (fallback): copy adj into output chunk 2
// ---------------------------------------------------------------------------
__global__ void adjcopy(const float* __restrict__ adj, float* __restrict__ dst, int n4) {
    int idx = blockIdx.x * blockDim.x + threadIdx.x;
    int stride = gridDim.x * blockDim.x;
    const float4* s = reinterpret_cast<const float4*>(adj);
    float4* d = reinterpret_cast<float4*>(dst);
    for (int i = idx; i < n4; i += stride) d[i] = s[i];
}

extern "C" void kernel_launch(void* const* d_in, const int* in_sizes, int n_in,
                              void* d_out, int out_size, void* d_ws, size_t ws_size,
                              hipStream_t stream) {
    const float* x    = (const float*)d_in[0];
    const float* adj  = (const float*)d_in[1];
    const float* Wp   = (const float*)d_in[2];
    const float* Ws   = (const float*)d_in[3];
    const float* bias = (const float*)d_in[4];
    float* out     = (float*)d_out;
    float* out_adj = out + (size_t)BATCH * SEQ * CH;

    const size_t nProj = (size_t)BATCH * SEQ * CH;
    const size_t nSc   = (size_t)BATCH * NHEADS * SEQ;
    const size_t need  = CH * CH * 2 + nProj * 2 + 2 * nSc * 4;
    const bool use_ws  = (ws_size >= need);
    char* scratch = use_ws ? (char*)d_ws : (char*)out_adj;
    unsigned short* WpT   = (unsigned short*)scratch;
    unsigned short* projT = (unsigned short*)(scratch + (size_t)CH * CH * 2);
    float*          sl    = (float*)(scratch + (size_t)CH * CH * 2 + nProj * 2);
    float*          sr    = sl + nSc;

    wpt_cast<<<dim3(8, 8), 256, 0, stream>>>(Wp, WpT);
    proj_fused<<<dim3(512), 256, 0, stream>>>(x, WpT, Ws, projT, sl, sr);
    if (use_ws) {
        attn10<true><<<dim3(512), 256, 0, stream>>>(
            x, adj, projT, sl, sr, Ws, bias, out, out_adj);
    } else {
        attn10<false><<<dim3(512), 256, 0, stream>>>(
            x, adj, projT, sl, sr, Ws, bias, out, out_adj);
        adjcopy<<<2048, 256, 0, stream>>>(adj, out_adj, (BATCH * SEQ * SEQ) / 4);
    }
}